// Round 1
// 549.727 us; speedup vs baseline: 1.2361x; 1.2361x over previous
//
#include <hip/hip_runtime.h>
#include <math.h>

typedef short bf8 __attribute__((ext_vector_type(8)));
typedef float f4  __attribute__((ext_vector_type(4)));

__device__ inline float b2f(unsigned short u) {
    return __uint_as_float(((unsigned int)u) << 16);
}
__device__ inline unsigned short f2b(float f) {
    unsigned int u = __float_as_uint(f);
    u = (u + 0x7fffu + ((u >> 16) & 1u)) >> 16;
    return (unsigned short)u;
}

// ---------------- K1: fused LayerNorm + transpose to bf16 [B, L, C] ----------------
// Block: 32 l-positions x 256 channels. Stats computed in-register during the
// coalesced load; fp32 tile staged in LDS (XOR swizzle: conflict-free both phases);
// output written as bf16 [b][l][c] (the MFMA B-operand wants contiguous k=C).
__global__ __launch_bounds__(256) void k_ln_t(const float* __restrict__ x,
                                              const float* __restrict__ g,
                                              const float* __restrict__ beta,
                                              unsigned short* __restrict__ xnb) {
    __shared__ float xt[32 * 261];   // pitch 261 (odd dword stride) + per-element XOR swizzle
    __shared__ float ps[8][32];
    __shared__ float ps2[8][32];
    __shared__ float ms[32];
    __shared__ float rs[32];
    int l0 = blockIdx.x * 32, b = blockIdx.y;
    int tid = threadIdx.x;
    int tl = tid & 31, c0 = tid >> 5;      // c0 in 0..7
    const float* xb = x + (size_t)b * 1048576 + l0 + tl;
    float s = 0.f, s2 = 0.f;
#pragma unroll 8
    for (int rr = 0; rr < 32; ++rr) {
        int c = rr * 8 + c0;
        float v = xb[(size_t)c * 4096];            // wave: 32 consecutive l, coalesced
        int cm = c ^ (((rr >> 2) & 7) << 2);       // swizzle bits2-4 by c-bits5-7
        xt[tl * 261 + cm] = v;
        s += v; s2 += v * v;
    }
    ps[c0][tl] = s; ps2[c0][tl] = s2;
    __syncthreads();
    if (tid < 32) {
        float t = 0.f, t2 = 0.f;
#pragma unroll
        for (int j = 0; j < 8; ++j) { t += ps[j][tid]; t2 += ps2[j][tid]; }
        float m = t * (1.f / 256.f);
        float var = t2 * (1.f / 256.f) - m * m;
        ms[tid] = m;
        rs[tid] = rsqrtf(var + 1e-4f);
    }
    __syncthreads();
    // write phase: thread owns (l = tid>>3, c-chunk = (tid&7)*32) -> 64B contiguous
    int lw = tid >> 3, cc = (tid & 7) * 32;
    int xr = (tid & 7) << 2;                        // = ((c>>5)&7)<<2 for this chunk
    float m = ms[lw], r = rs[lw];
    unsigned short* dst = xnb + ((size_t)b * 4096 + l0 + lw) * 256 + cc;
#pragma unroll
    for (int q4 = 0; q4 < 4; ++q4) {
        int cb = cc + q4 * 8;
        float gv[8], bv[8];
        *(float4*)(gv)     = *(const float4*)(g + cb);
        *(float4*)(gv + 4) = *(const float4*)(g + cb + 4);
        *(float4*)(bv)     = *(const float4*)(beta + cb);
        *(float4*)(bv + 4) = *(const float4*)(beta + cb + 4);
        union { unsigned short u[8]; uint4 v; } pk;
#pragma unroll
        for (int e = 0; e < 8; ++e) {
            int cm = (cb + e) ^ xr;
            pk.u[e] = f2b((xt[lw * 261 + cm] - m) * r * gv[e] + bv[e]);
        }
        *(uint4*)(dst + q4 * 8) = pk.v;
    }
}

// ---------------- K2: wqkv fp32 -> bf16 ----------------
__global__ __launch_bounds__(256) void k_wcvt(const float* __restrict__ w,
                                              unsigned short* __restrict__ wb) {
    int i = (blockIdx.x * 256 + threadIdx.x) * 8;
    float4 a = *(const float4*)(w + i);
    float4 c = *(const float4*)(w + i + 4);
    union { unsigned short u[8]; uint4 v; } r;
    r.u[0] = f2b(a.x); r.u[1] = f2b(a.y); r.u[2] = f2b(a.z); r.u[3] = f2b(a.w);
    r.u[4] = f2b(c.x); r.u[5] = f2b(c.y); r.u[6] = f2b(c.z); r.u[7] = f2b(c.w);
    *(uint4*)(wb + i) = r.v;
}

// ---------------- K3: qkv GEMM (bf16 MFMA) + window-layout scatter ----------------
// Block: 64 j x 256 l tile, 4 waves (wave w owns l sub-tile w*64..w*64+63).
// No LDS: A-frags from wb [j][k] row-major, B-frags from xnb [b][l][k] (k contiguous).
// q,k -> [branch][bw][head][pos][d] bf16 (q pre-scaled 0.125); v -> [branch][bw][head][d][pos].
__global__ __launch_bounds__(256) void k_qkv(const unsigned short* __restrict__ wb,
                                             const unsigned short* __restrict__ xnb,
                                             unsigned short* __restrict__ qw,
                                             unsigned short* __restrict__ kw,
                                             unsigned short* __restrict__ vw) {
    int jt = blockIdx.x, lt = blockIdx.y, b = blockIdx.z;
    int tid = threadIdx.x;
    int w = tid >> 6, lane = tid & 63;
    int ln15 = lane & 15, quad = lane >> 4;
    const unsigned short* A = wb + (size_t)jt * 64 * 256 + ln15 * 256 + quad * 8;
    const unsigned short* B = xnb + ((size_t)b * 4096 + lt * 256 + w * 64 + ln15) * 256 + quad * 8;
    const f4 z = {0.f, 0.f, 0.f, 0.f};
    f4 acc[4][4];
#pragma unroll
    for (int i = 0; i < 4; i++)
#pragma unroll
        for (int j = 0; j < 4; j++) acc[i][j] = z;
#pragma unroll 2
    for (int k0 = 0; k0 < 256; k0 += 32) {
        bf8 af[4], bvf[4];
#pragma unroll
        for (int i = 0; i < 4; i++) af[i]  = *(const bf8*)(A + i * 16 * 256 + k0);
#pragma unroll
        for (int j = 0; j < 4; j++) bvf[j] = *(const bf8*)(B + j * 16 * 256 + k0);
#pragma unroll
        for (int i = 0; i < 4; i++)
#pragma unroll
            for (int j = 0; j < 4; j++)
                acc[i][j] = __builtin_amdgcn_mfma_f32_16x16x32_bf16(af[i], bvf[j], acc[i][j], 0, 0, 0);
    }
    // epilogue: C frag layout col=lane&15 (l), row=quad*4+reg (j). sel/branch are
    // wave-uniform (64-j tile never crosses a 256- or 128-boundary); head==reg.
    int lbase = lt * 256 + w * 64;
#pragma unroll
    for (int i = 0; i < 4; i++) {
#pragma unroll
        for (int r = 0; r < 4; r++) {
            int j = jt * 64 + i * 16 + quad * 4 + r;
            int sel = j >> 8;                 // 0=q 1=k 2=v (uniform)
            int jr = j & 255;
            int branch = jr >> 7;             // uniform
            int chb = jr & 127;
            int d = chb >> 2, head = chb & 3; // head == r; d = (jt&1)*16 + i*4 + quad
            unsigned short* dst = (sel == 0) ? qw : ((sel == 1) ? kw : vw);
            float sc = (sel == 0) ? 0.125f : 1.f;
#pragma unroll
            for (int jf = 0; jf < 4; jf++) {
                int ll = lbase + jf * 16 + ln15;
                int row = ll >> 6, col = ll & 63;
                int win, pos;
                if (branch == 0) { win = col >> 2; pos = (row << 2) | (col & 3); }
                else             { win = row >> 2; pos = ((row & 3) << 6) | col; }
                int bw = b * 16 + win;
                size_t idx;
                if (sel == 2)
                    idx = ((((size_t)branch * 128 + bw) * 4 + head) * 32 + d) * 256 + pos;
                else
                    idx = ((((size_t)branch * 128 + bw) * 4 + head) * 256 + pos) * 32 + d;
                dst[idx] = f2b(acc[i][jf][r] * sc);
            }
        }
    }
}

// ---------------- K4: MFMA attention + LePE (unchanged) ----------------
__global__ __launch_bounds__(256, 3) void k_attn(const unsigned short* __restrict__ qw,
                                                 const unsigned short* __restrict__ kw,
                                                 const unsigned short* __restrict__ vw,
                                                 const float* __restrict__ lw1,
                                                 const float* __restrict__ lb1,
                                                 const float* __restrict__ lw2,
                                                 const float* __restrict__ lb2,
                                                 float* __restrict__ attn_out,
                                                 float* __restrict__ xcat) {
    __shared__ __align__(16) char smem[49792];
    float*          olds = (float*)smem;            // 32*257 floats = 32896 B (O transpose; first 4KB = P staging)
    unsigned short* vt   = (unsigned short*)(smem + 32896);  // 32 rows * pitch 264 bf16 = 16896 B

    int bid = blockIdx.x;
    int branch = bid >> 9;
    int bw = (bid >> 2) & 127;
    int head = bid & 3;
    int tid = threadIdx.x;
    int w = tid >> 6, lane = tid & 63;
    int ln15 = lane & 15, quad = lane >> 4;
    int rowbase = w * 64;

    size_t base = (((size_t)branch * 128 + bw) * 4 + head) * 8192;
    const unsigned short* qb = qw + base;   // [pos][d]
    const unsigned short* kb = kw + base;   // [pos][d]
    const unsigned short* vb = vw + base;   // [d][pos]

    // stage V into LDS (pitch 264)
    {
        int d = tid >> 3, ck = (tid & 7) * 32;
        const uint4* s = (const uint4*)(vb + d * 256 + ck);
        uint4* dst = (uint4*)(vt + d * 264 + ck);
        dst[0] = s[0]; dst[1] = s[1]; dst[2] = s[2]; dst[3] = s[3];
    }

    // Q fragments (A-layout): lane holds Q[row=ln15][k=quad*8..+8]
    bf8 qf[4];
#pragma unroll
    for (int rt = 0; rt < 4; rt++)
        qf[rt] = *(const bf8*)(qb + (rowbase + rt * 16 + ln15) * 32 + quad * 8);

    const f4 z = {0.f, 0.f, 0.f, 0.f};

    // ---- pass 1: row sums of exp(s) ----
    f4 lsum[4] = {z, z, z, z};
    for (int jtile = 0; jtile < 16; jtile++) {
        bf8 kf = *(const bf8*)(kb + (jtile * 16 + ln15) * 32 + quad * 8);
#pragma unroll
        for (int rt = 0; rt < 4; rt++) {
            f4 s = __builtin_amdgcn_mfma_f32_16x16x32_bf16(qf[rt], kf, z, 0, 0, 0);
            lsum[rt].x += __expf(s.x);
            lsum[rt].y += __expf(s.y);
            lsum[rt].z += __expf(s.z);
            lsum[rt].w += __expf(s.w);
        }
    }
    f4 inv[4];
#pragma unroll
    for (int rt = 0; rt < 4; rt++) {
        float a0 = lsum[rt].x, a1 = lsum[rt].y, a2 = lsum[rt].z, a3 = lsum[rt].w;
#pragma unroll
        for (int m = 1; m < 16; m <<= 1) {
            a0 += __shfl_xor(a0, m); a1 += __shfl_xor(a1, m);
            a2 += __shfl_xor(a2, m); a3 += __shfl_xor(a3, m);
        }
        inv[rt].x = 1.f / a0; inv[rt].y = 1.f / a1;
        inv[rt].z = 1.f / a2; inv[rt].w = 1.f / a3;
    }

    __syncthreads();   // V staged before any vt read

    // ---- pass 2: recompute S, write attn, PV via MFMA ----
    unsigned short* plw = ((unsigned short*)olds) + w * 512;  // 16x32 bf16 P staging per wave
    float* abase = attn_out + (size_t)branch * 33554432ull
                 + ((size_t)(bw * 4 + head)) * 65536;
    f4 oacc[4][2] = {{z, z}, {z, z}, {z, z}, {z, z}};
    for (int t = 0; t < 8; t++) {
        int c0 = t * 32;
        bf8 kf0 = *(const bf8*)(kb + (c0 + ln15) * 32 + quad * 8);
        bf8 kf1 = *(const bf8*)(kb + (c0 + 16 + ln15) * 32 + quad * 8);
        bf8 vf0 = *(const bf8*)(vt + ln15 * 264 + c0 + quad * 8);
        bf8 vf1 = *(const bf8*)(vt + (16 + ln15) * 264 + c0 + quad * 8);
#pragma unroll
        for (int rt = 0; rt < 4; rt++) {
            f4 s0 = __builtin_amdgcn_mfma_f32_16x16x32_bf16(qf[rt], kf0, z, 0, 0, 0);
            f4 s1 = __builtin_amdgcn_mfma_f32_16x16x32_bf16(qf[rt], kf1, z, 0, 0, 0);
            f4 p0, p1;
            p0.x = __expf(s0.x) * inv[rt].x; p0.y = __expf(s0.y) * inv[rt].y;
            p0.z = __expf(s0.z) * inv[rt].z; p0.w = __expf(s0.w) * inv[rt].w;
            p1.x = __expf(s1.x) * inv[rt].x; p1.y = __expf(s1.y) * inv[rt].y;
            p1.z = __expf(s1.z) * inv[rt].z; p1.w = __expf(s1.w) * inv[rt].w;
            float* ar = abase + (size_t)(rowbase + rt * 16 + quad * 4) * 256 + c0 + ln15;
            ar[0]   = p0.x; ar[256] = p0.y; ar[512] = p0.z; ar[768] = p0.w;
            ar[16]  = p1.x; ar[272] = p1.y; ar[528] = p1.z; ar[784] = p1.w;
            // stage P (bf16, A-layout source tile 16 rows x 32 cols, pitch 32)
            plw[(quad * 4 + 0) * 32 + ln15]      = f2b(p0.x);
            plw[(quad * 4 + 1) * 32 + ln15]      = f2b(p0.y);
            plw[(quad * 4 + 2) * 32 + ln15]      = f2b(p0.z);
            plw[(quad * 4 + 3) * 32 + ln15]      = f2b(p0.w);
            plw[(quad * 4 + 0) * 32 + 16 + ln15] = f2b(p1.x);
            plw[(quad * 4 + 1) * 32 + 16 + ln15] = f2b(p1.y);
            plw[(quad * 4 + 2) * 32 + 16 + ln15] = f2b(p1.z);
            plw[(quad * 4 + 3) * 32 + 16 + ln15] = f2b(p1.w);
            bf8 pf = *(const bf8*)(plw + ln15 * 32 + quad * 8);
            oacc[rt][0] = __builtin_amdgcn_mfma_f32_16x16x32_bf16(pf, vf0, oacc[rt][0], 0, 0, 0);
            oacc[rt][1] = __builtin_amdgcn_mfma_f32_16x16x32_bf16(pf, vf1, oacc[rt][1], 0, 0, 0);
        }
    }

    __syncthreads();   // all P staging reads done before O overwrites olds
    // O (C-layout) -> olds[d * 257 + pos]
#pragma unroll
    for (int rt = 0; rt < 4; rt++)
#pragma unroll
        for (int dt = 0; dt < 2; dt++) {
            int d = dt * 16 + ln15;
            int r = rowbase + rt * 16 + quad * 4;
            olds[d * 257 + r + 0] = oacc[rt][dt][0];
            olds[d * 257 + r + 1] = oacc[rt][dt][1];
            olds[d * 257 + r + 2] = oacc[rt][dt][2];
            olds[d * 257 + r + 3] = oacc[rt][dt][3];
        }
    __syncthreads();

    // ---- LePE + xcat write: thread = position ----
    const float* lw = branch ? lw2 : lw1;
    const float* lb = branch ? lb2 : lb1;
    int p = tid;
    int hs, ws_;
    if (branch == 0) { hs = p >> 2; ws_ = p & 3; }
    else             { hs = p >> 6; ws_ = p & 63; }
    int win = bw & 15, b = bw >> 4;
    int row, col;
    if (branch == 0) { row = p >> 2; col = (win << 2) | (p & 3); }
    else             { row = (win << 2) | (p >> 6); col = p & 63; }
    size_t lpix = (size_t)row * 64 + col;
#pragma unroll
    for (int d = 0; d < 32; ++d) {
        float acc = lb[d * 4 + head];
#pragma unroll
        for (int ky = 0; ky < 3; ky++) {
#pragma unroll
            for (int kx = 0; kx < 3; kx++) {
                int ny = hs + ky - 1, nx = ws_ + kx - 1;
                bool ok; int np;
                if (branch == 0) { ok = (ny >= 0 && ny < 64 && nx >= 0 && nx < 4);  np = (ny << 2) | (nx & 3); }
                else             { ok = (ny >= 0 && ny < 4  && nx >= 0 && nx < 64); np = (ny << 6) | (nx & 63); }
                if (ok) acc += lw[(d * 4 + head) * 9 + ky * 3 + kx] * b2f(vt[d * 264 + np]);
            }
        }
        float oval = olds[d * 257 + p] + acc;
        int chg = branch * 128 + d * 4 + head;
        xcat[((size_t)b * 256 + chg) * 4096 + lpix] = oval;
    }
}

// ---------------- K5: projection GEMM (unchanged) ----------------
__global__ __launch_bounds__(256) void k_proj(const float* __restrict__ pw,
                                              const float* __restrict__ pb,
                                              const float* __restrict__ xcat,
                                              float* __restrict__ out) {
    __shared__ float sA[16][68];
    __shared__ float sB[16][68];
    int jt = blockIdx.x, lt = blockIdx.y, b = blockIdx.z;
    int j0 = jt * 64, l0 = lt * 64;
    int tid = threadIdx.x;
    float acc[4][4] = {};
    int ar = tid >> 2, ac4 = (tid & 3) << 2;
    int tl = tid & 63;
    for (int k0 = 0; k0 < 256; k0 += 16) {
        float4 av = *(const float4*)(pw + (size_t)(j0 + ar) * 256 + k0 + ac4);
        sA[ac4 + 0][ar] = av.x; sA[ac4 + 1][ar] = av.y;
        sA[ac4 + 2][ar] = av.z; sA[ac4 + 3][ar] = av.w;
#pragma unroll
        for (int i = 0; i < 4; i++) {
            int kr = (tid >> 6) + i * 4;
            sB[kr][tl] = xcat[((size_t)b * 256 + k0 + kr) * 4096 + l0 + tl];
        }
        __syncthreads();
#pragma unroll
        for (int kk = 0; kk < 16; ++kk) {
            float4 a4 = *(const float4*)&sA[kk][(tid >> 4) << 2];
            float4 b4 = *(const float4*)&sB[kk][(tid & 15) << 2];
            acc[0][0] += a4.x * b4.x; acc[0][1] += a4.x * b4.y; acc[0][2] += a4.x * b4.z; acc[0][3] += a4.x * b4.w;
            acc[1][0] += a4.y * b4.x; acc[1][1] += a4.y * b4.y; acc[1][2] += a4.y * b4.z; acc[1][3] += a4.y * b4.w;
            acc[2][0] += a4.z * b4.x; acc[2][1] += a4.z * b4.y; acc[2][2] += a4.z * b4.z; acc[2][3] += a4.z * b4.w;
            acc[3][0] += a4.w * b4.x; acc[3][1] += a4.w * b4.y; acc[3][2] += a4.w * b4.z; acc[3][3] += a4.w * b4.w;
        }
        __syncthreads();
    }
#pragma unroll
    for (int i = 0; i < 4; i++) {
        int jj = j0 + ((tid >> 4) << 2) + i;
        float bias = pb[jj];
        float4 r4;
        r4.x = acc[i][0] + bias; r4.y = acc[i][1] + bias;
        r4.z = acc[i][2] + bias; r4.w = acc[i][3] + bias;
        *(float4*)(out + ((size_t)b * 256 + jj) * 4096 + l0 + ((tid & 15) << 2)) = r4;
    }
}

extern "C" void kernel_launch(void* const* d_in, const int* in_sizes, int n_in,
                              void* d_out, int out_size, void* d_ws, size_t ws_size,
                              hipStream_t stream) {
    const float* x    = (const float*)d_in[0];
    const float* ln_g = (const float*)d_in[1];
    const float* ln_b = (const float*)d_in[2];
    const float* wqkv = (const float*)d_in[3];
    const float* pw   = (const float*)d_in[4];
    const float* pb   = (const float*)d_in[5];
    const float* lw1  = (const float*)d_in[6];
    const float* lb1  = (const float*)d_in[7];
    const float* lw2  = (const float*)d_in[8];
    const float* lb2  = (const float*)d_in[9];

    float* ws = (float*)d_ws;
    // Workspace layout (same footprint as before):
    //   [ws .. ws+65536)           : (old mu/rstd slots, now unused)
    //   [ws+65536 .. +8388608 fl)  : xn region, reused as: xnb bf16 (8,388,608 shorts)
    //                                + wb bf16 (196,608 shorts); later overwritten as xcat fp32
    //   qw/kw/vw                   : unchanged
    unsigned short* xnb = (unsigned short*)(ws + 65536);
    unsigned short* wb  = xnb + 8388608;
    unsigned short* qw  = (unsigned short*)(ws + 65536 + 8388608);
    unsigned short* kw  = qw + 8388608;
    unsigned short* vw  = kw + 8388608;
    float* xcat = ws + 65536;
    float* out  = (float*)d_out;
    float* attn = out + 8388608;

    k_wcvt<<<96, 256, 0, stream>>>(wqkv, wb);
    k_ln_t<<<dim3(128, 8), 256, 0, stream>>>(x, ln_g, ln_b, xnb);
    k_qkv<<<dim3(12, 16, 8), 256, 0, stream>>>(wb, xnb, qw, kw, vw);
    k_attn<<<1024, 256, 0, stream>>>(qw, kw, vw, lw1, lb1, lw2, lb2, attn, xcat);
    k_proj<<<dim3(4, 64, 8), 256, 0, stream>>>(pw, pb, xcat, out);
}

// Round 3
// 518.636 us; speedup vs baseline: 1.3102x; 1.0599x over previous
//
#include <hip/hip_runtime.h>
#include <math.h>

typedef short bf8 __attribute__((ext_vector_type(8)));
typedef float f4  __attribute__((ext_vector_type(4)));

__device__ inline float b2f(unsigned short u) {
    return __uint_as_float(((unsigned int)u) << 16);
}
__device__ inline unsigned short f2b(float f) {
    unsigned int u = __float_as_uint(f);
    u = (u + 0x7fffu + ((u >> 16) & 1u)) >> 16;
    return (unsigned short)u;
}

// ---------------- K1: fused LayerNorm + transpose to bf16 [B, L, C] ----------------
__global__ __launch_bounds__(256) void k_ln_t(const float* __restrict__ x,
                                              const float* __restrict__ g,
                                              const float* __restrict__ beta,
                                              unsigned short* __restrict__ xnb) {
    __shared__ float xt[32 * 261];   // pitch 261 (odd dword stride) + per-element XOR swizzle
    __shared__ float ps[8][32];
    __shared__ float ps2[8][32];
    __shared__ float ms[32];
    __shared__ float rs[32];
    int l0 = blockIdx.x * 32, b = blockIdx.y;
    int tid = threadIdx.x;
    int tl = tid & 31, c0 = tid >> 5;      // c0 in 0..7
    const float* xb = x + (size_t)b * 1048576 + l0 + tl;
    float s = 0.f, s2 = 0.f;
#pragma unroll 8
    for (int rr = 0; rr < 32; ++rr) {
        int c = rr * 8 + c0;
        float v = xb[(size_t)c * 4096];            // wave: 32 consecutive l, coalesced
        int cm = c ^ (((rr >> 2) & 7) << 2);       // swizzle bits2-4 by c-bits5-7
        xt[tl * 261 + cm] = v;
        s += v; s2 += v * v;
    }
    ps[c0][tl] = s; ps2[c0][tl] = s2;
    __syncthreads();
    if (tid < 32) {
        float t = 0.f, t2 = 0.f;
#pragma unroll
        for (int j = 0; j < 8; ++j) { t += ps[j][tid]; t2 += ps2[j][tid]; }
        float m = t * (1.f / 256.f);
        float var = t2 * (1.f / 256.f) - m * m;
        ms[tid] = m;
        rs[tid] = rsqrtf(var + 1e-4f);
    }
    __syncthreads();
    // write phase: thread owns (l = tid>>3, c-chunk = (tid&7)*32) -> 64B contiguous
    int lw = tid >> 3, cc = (tid & 7) * 32;
    int xr = (tid & 7) << 2;                        // = ((c>>5)&7)<<2 for this chunk
    float m = ms[lw], r = rs[lw];
    unsigned short* dst = xnb + ((size_t)b * 4096 + l0 + lw) * 256 + cc;
#pragma unroll
    for (int q4 = 0; q4 < 4; ++q4) {
        int cb = cc + q4 * 8;
        float gv[8], bv[8];
        *(float4*)(gv)     = *(const float4*)(g + cb);
        *(float4*)(gv + 4) = *(const float4*)(g + cb + 4);
        *(float4*)(bv)     = *(const float4*)(beta + cb);
        *(float4*)(bv + 4) = *(const float4*)(beta + cb + 4);
        union { unsigned short u[8]; uint4 v; } pk;
#pragma unroll
        for (int e = 0; e < 8; ++e) {
            int cm = (cb + e) ^ xr;
            pk.u[e] = f2b((xt[lw * 261 + cm] - m) * r * gv[e] + bv[e]);
        }
        *(uint4*)(dst + q4 * 8) = pk.v;
    }
}

// ---------------- K2a: wqkv fp32 -> bf16 ----------------
__global__ __launch_bounds__(256) void k_wcvt(const float* __restrict__ w,
                                              unsigned short* __restrict__ wb) {
    int i = (blockIdx.x * 256 + threadIdx.x) * 8;
    float4 a = *(const float4*)(w + i);
    float4 c = *(const float4*)(w + i + 4);
    union { unsigned short u[8]; uint4 v; } r;
    r.u[0] = f2b(a.x); r.u[1] = f2b(a.y); r.u[2] = f2b(a.z); r.u[3] = f2b(a.w);
    r.u[4] = f2b(c.x); r.u[5] = f2b(c.y); r.u[6] = f2b(c.z); r.u[7] = f2b(c.w);
    *(uint4*)(wb + i) = r.v;
}

// ---------------- K2b: proj_w fp32 -> bf16 with head-grouped column permutation ----
// pwb[o][c'] = pw[o][c], c' = br*128 + head*32 + d  <->  c = br*128 + d*4 + head
__global__ __launch_bounds__(256) void k_pcvt(const float* __restrict__ pw,
                                              unsigned short* __restrict__ pwb) {
    int idx = blockIdx.x * 256 + threadIdx.x;   // 65536 total
    int o = idx >> 8, cp = idx & 255;
    int br = cp >> 7, head = (cp >> 5) & 3, d = cp & 31;
    int c = br * 128 + d * 4 + head;
    pwb[idx] = f2b(pw[o * 256 + c]);
}

// ---------------- K3: qkv GEMM (bf16 MFMA) + window-layout scatter ----------------
__global__ __launch_bounds__(256) void k_qkv(const unsigned short* __restrict__ wb,
                                             const unsigned short* __restrict__ xnb,
                                             unsigned short* __restrict__ qw,
                                             unsigned short* __restrict__ kw,
                                             unsigned short* __restrict__ vw) {
    int jt = blockIdx.x, lt = blockIdx.y, b = blockIdx.z;
    int tid = threadIdx.x;
    int w = tid >> 6, lane = tid & 63;
    int ln15 = lane & 15, quad = lane >> 4;
    const unsigned short* A = wb + (size_t)jt * 64 * 256 + ln15 * 256 + quad * 8;
    const unsigned short* B = xnb + ((size_t)b * 4096 + lt * 256 + w * 64 + ln15) * 256 + quad * 8;
    const f4 z = {0.f, 0.f, 0.f, 0.f};
    f4 acc[4][4];
#pragma unroll
    for (int i = 0; i < 4; i++)
#pragma unroll
        for (int j = 0; j < 4; j++) acc[i][j] = z;
#pragma unroll 2
    for (int k0 = 0; k0 < 256; k0 += 32) {
        bf8 af[4], bvf[4];
#pragma unroll
        for (int i = 0; i < 4; i++) af[i]  = *(const bf8*)(A + i * 16 * 256 + k0);
#pragma unroll
        for (int j = 0; j < 4; j++) bvf[j] = *(const bf8*)(B + j * 16 * 256 + k0);
#pragma unroll
        for (int i = 0; i < 4; i++)
#pragma unroll
            for (int j = 0; j < 4; j++)
                acc[i][j] = __builtin_amdgcn_mfma_f32_16x16x32_bf16(af[i], bvf[j], acc[i][j], 0, 0, 0);
    }
    int lbase = lt * 256 + w * 64;
#pragma unroll
    for (int i = 0; i < 4; i++) {
#pragma unroll
        for (int r = 0; r < 4; r++) {
            int j = jt * 64 + i * 16 + quad * 4 + r;
            int sel = j >> 8;                 // 0=q 1=k 2=v (uniform)
            int jr = j & 255;
            int branch = jr >> 7;             // uniform
            int chb = jr & 127;
            int d = chb >> 2, head = chb & 3;
            unsigned short* dst = (sel == 0) ? qw : ((sel == 1) ? kw : vw);
            float sc = (sel == 0) ? 0.125f : 1.f;
#pragma unroll
            for (int jf = 0; jf < 4; jf++) {
                int ll = lbase + jf * 16 + ln15;
                int row = ll >> 6, col = ll & 63;
                int win, pos;
                if (branch == 0) { win = col >> 2; pos = (row << 2) | (col & 3); }
                else             { win = row >> 2; pos = ((row & 3) << 6) | col; }
                int bw = b * 16 + win;
                size_t idx;
                if (sel == 2)
                    idx = ((((size_t)branch * 128 + bw) * 4 + head) * 32 + d) * 256 + pos;
                else
                    idx = ((((size_t)branch * 128 + bw) * 4 + head) * 256 + pos) * 32 + d;
                dst[idx] = f2b(acc[i][jf][r] * sc);
            }
        }
    }
}

// ---------------- K4: MFMA attention + LePE ----------------
// xcat bf16 [b][l][c'], c' = branch*128 + head*32 + d (head-grouped -> 64B
// contiguous per thread-position, written as 4x uint4).
__global__ __launch_bounds__(256, 3) void k_attn(const unsigned short* __restrict__ qw,
                                                 const unsigned short* __restrict__ kw,
                                                 const unsigned short* __restrict__ vw,
                                                 const float* __restrict__ lw1,
                                                 const float* __restrict__ lb1,
                                                 const float* __restrict__ lw2,
                                                 const float* __restrict__ lb2,
                                                 float* __restrict__ attn_out,
                                                 unsigned short* __restrict__ xcat) {
    __shared__ __align__(16) char smem[49792];
    float*          olds = (float*)smem;            // 32*257 floats (O transpose; first 4KB = P staging)
    unsigned short* vt   = (unsigned short*)(smem + 32896);  // 32 rows * pitch 264 bf16

    int bid = blockIdx.x;
    int branch = bid >> 9;
    int bw = (bid >> 2) & 127;
    int head = bid & 3;
    int tid = threadIdx.x;
    int w = tid >> 6, lane = tid & 63;
    int ln15 = lane & 15, quad = lane >> 4;
    int rowbase = w * 64;

    size_t base = (((size_t)branch * 128 + bw) * 4 + head) * 8192;
    const unsigned short* qb = qw + base;   // [pos][d]
    const unsigned short* kb = kw + base;   // [pos][d]
    const unsigned short* vb = vw + base;   // [d][pos]

    // stage V into LDS (pitch 264)
    {
        int d = tid >> 3, ck = (tid & 7) * 32;
        const uint4* s = (const uint4*)(vb + d * 256 + ck);
        uint4* dst = (uint4*)(vt + d * 264 + ck);
        dst[0] = s[0]; dst[1] = s[1]; dst[2] = s[2]; dst[3] = s[3];
    }

    // Q fragments (A-layout): lane holds Q[row=ln15][k=quad*8..+8]
    bf8 qf[4];
#pragma unroll
    for (int rt = 0; rt < 4; rt++)
        qf[rt] = *(const bf8*)(qb + (rowbase + rt * 16 + ln15) * 32 + quad * 8);

    const f4 z = {0.f, 0.f, 0.f, 0.f};

    // ---- pass 1: row sums of exp(s) ----
    f4 lsum[4] = {z, z, z, z};
    for (int jtile = 0; jtile < 16; jtile++) {
        bf8 kf = *(const bf8*)(kb + (jtile * 16 + ln15) * 32 + quad * 8);
#pragma unroll
        for (int rt = 0; rt < 4; rt++) {
            f4 s = __builtin_amdgcn_mfma_f32_16x16x32_bf16(qf[rt], kf, z, 0, 0, 0);
            lsum[rt].x += __expf(s.x);
            lsum[rt].y += __expf(s.y);
            lsum[rt].z += __expf(s.z);
            lsum[rt].w += __expf(s.w);
        }
    }
    f4 inv[4];
#pragma unroll
    for (int rt = 0; rt < 4; rt++) {
        float a0 = lsum[rt].x, a1 = lsum[rt].y, a2 = lsum[rt].z, a3 = lsum[rt].w;
#pragma unroll
        for (int m = 1; m < 16; m <<= 1) {
            a0 += __shfl_xor(a0, m); a1 += __shfl_xor(a1, m);
            a2 += __shfl_xor(a2, m); a3 += __shfl_xor(a3, m);
        }
        inv[rt].x = 1.f / a0; inv[rt].y = 1.f / a1;
        inv[rt].z = 1.f / a2; inv[rt].w = 1.f / a3;
    }

    __syncthreads();   // V staged before any vt read

    // ---- pass 2: recompute S, write attn, PV via MFMA ----
    unsigned short* plw = ((unsigned short*)olds) + w * 512;  // 16x32 bf16 P staging per wave
    float* abase = attn_out + (size_t)branch * 33554432ull
                 + ((size_t)(bw * 4 + head)) * 65536;
    f4 oacc[4][2] = {{z, z}, {z, z}, {z, z}, {z, z}};
    for (int t = 0; t < 8; t++) {
        int c0 = t * 32;
        bf8 kf0 = *(const bf8*)(kb + (c0 + ln15) * 32 + quad * 8);
        bf8 kf1 = *(const bf8*)(kb + (c0 + 16 + ln15) * 32 + quad * 8);
        bf8 vf0 = *(const bf8*)(vt + ln15 * 264 + c0 + quad * 8);
        bf8 vf1 = *(const bf8*)(vt + (16 + ln15) * 264 + c0 + quad * 8);
#pragma unroll
        for (int rt = 0; rt < 4; rt++) {
            f4 s0 = __builtin_amdgcn_mfma_f32_16x16x32_bf16(qf[rt], kf0, z, 0, 0, 0);
            f4 s1 = __builtin_amdgcn_mfma_f32_16x16x32_bf16(qf[rt], kf1, z, 0, 0, 0);
            f4 p0, p1;
            p0.x = __expf(s0.x) * inv[rt].x; p0.y = __expf(s0.y) * inv[rt].y;
            p0.z = __expf(s0.z) * inv[rt].z; p0.w = __expf(s0.w) * inv[rt].w;
            p1.x = __expf(s1.x) * inv[rt].x; p1.y = __expf(s1.y) * inv[rt].y;
            p1.z = __expf(s1.z) * inv[rt].z; p1.w = __expf(s1.w) * inv[rt].w;
            float* ar = abase + (size_t)(rowbase + rt * 16 + quad * 4) * 256 + c0 + ln15;
            ar[0]   = p0.x; ar[256] = p0.y; ar[512] = p0.z; ar[768] = p0.w;
            ar[16]  = p1.x; ar[272] = p1.y; ar[528] = p1.z; ar[784] = p1.w;
            // stage P (bf16, A-layout source tile 16 rows x 32 cols, pitch 32)
            plw[(quad * 4 + 0) * 32 + ln15]      = f2b(p0.x);
            plw[(quad * 4 + 1) * 32 + ln15]      = f2b(p0.y);
            plw[(quad * 4 + 2) * 32 + ln15]      = f2b(p0.z);
            plw[(quad * 4 + 3) * 32 + ln15]      = f2b(p0.w);
            plw[(quad * 4 + 0) * 32 + 16 + ln15] = f2b(p1.x);
            plw[(quad * 4 + 1) * 32 + 16 + ln15] = f2b(p1.y);
            plw[(quad * 4 + 2) * 32 + 16 + ln15] = f2b(p1.z);
            plw[(quad * 4 + 3) * 32 + 16 + ln15] = f2b(p1.w);
            bf8 pf = *(const bf8*)(plw + ln15 * 32 + quad * 8);
            oacc[rt][0] = __builtin_amdgcn_mfma_f32_16x16x32_bf16(pf, vf0, oacc[rt][0], 0, 0, 0);
            oacc[rt][1] = __builtin_amdgcn_mfma_f32_16x16x32_bf16(pf, vf1, oacc[rt][1], 0, 0, 0);
        }
    }

    __syncthreads();   // all P staging reads done before O overwrites olds
    // O (C-layout) -> olds[d * 257 + pos]
#pragma unroll
    for (int rt = 0; rt < 4; rt++)
#pragma unroll
        for (int dt = 0; dt < 2; dt++) {
            int d = dt * 16 + ln15;
            int r = rowbase + rt * 16 + quad * 4;
            olds[d * 257 + r + 0] = oacc[rt][dt][0];
            olds[d * 257 + r + 1] = oacc[rt][dt][1];
            olds[d * 257 + r + 2] = oacc[rt][dt][2];
            olds[d * 257 + r + 3] = oacc[rt][dt][3];
        }
    __syncthreads();

    // ---- LePE + xcat write: thread = position; bf16 [b][l][c'] head-grouped ----
    const float* lw = branch ? lw2 : lw1;
    const float* lb = branch ? lb2 : lb1;
    int p = tid;
    int hs, ws_;
    if (branch == 0) { hs = p >> 2; ws_ = p & 3; }
    else             { hs = p >> 6; ws_ = p & 63; }
    int win = bw & 15, b = bw >> 4;
    int row, col;
    if (branch == 0) { row = p >> 2; col = (win << 2) | (p & 3); }
    else             { row = (win << 2) | (p >> 6); col = p & 63; }
    size_t lpix = (size_t)row * 64 + col;
    unsigned short* xd = xcat + (((size_t)b * 4096 + lpix) * 256) + branch * 128 + head * 32;
#pragma unroll
    for (int dg = 0; dg < 4; ++dg) {
        union { unsigned short u[8]; uint4 v; } pk;
#pragma unroll
        for (int dd = 0; dd < 8; ++dd) {
            int d = dg * 8 + dd;
            float acc = lb[d * 4 + head];
#pragma unroll
            for (int ky = 0; ky < 3; ky++) {
#pragma unroll
                for (int kx = 0; kx < 3; kx++) {
                    int ny = hs + ky - 1, nx = ws_ + kx - 1;
                    bool ok; int np;
                    if (branch == 0) { ok = (ny >= 0 && ny < 64 && nx >= 0 && nx < 4);  np = (ny << 2) | (nx & 3); }
                    else             { ok = (ny >= 0 && ny < 4  && nx >= 0 && nx < 64); np = (ny << 6) | (nx & 63); }
                    if (ok) acc += lw[(d * 4 + head) * 9 + ky * 3 + kx] * b2f(vt[d * 264 + np]);
                }
            }
            pk.u[dd] = f2b(olds[d * 257 + p] + acc);
        }
        *(uint4*)(xd + dg * 8) = pk.v;
    }
}

// ---------------- K5: projection GEMM (bf16 MFMA) ----------------
// out[b][j][l] = sum_c' pwb[j][c'] * xcat[b][l][c'] + pb[j]
__global__ __launch_bounds__(256) void k_proj(const unsigned short* __restrict__ pwb,
                                              const float* __restrict__ pb,
                                              const unsigned short* __restrict__ xcat,
                                              float* __restrict__ out) {
    int jt = blockIdx.x, lt = blockIdx.y, b = blockIdx.z;
    int tid = threadIdx.x;
    int w = tid >> 6, lane = tid & 63;
    int ln15 = lane & 15, quad = lane >> 4;
    const unsigned short* A = pwb + (size_t)jt * 64 * 256 + ln15 * 256 + quad * 8;
    const unsigned short* B = xcat + ((size_t)b * 4096 + lt * 256 + w * 64 + ln15) * 256 + quad * 8;
    const f4 z = {0.f, 0.f, 0.f, 0.f};
    f4 acc[4][4];
#pragma unroll
    for (int i = 0; i < 4; i++)
#pragma unroll
        for (int j = 0; j < 4; j++) acc[i][j] = z;
#pragma unroll 2
    for (int k0 = 0; k0 < 256; k0 += 32) {
        bf8 af[4], bvf[4];
#pragma unroll
        for (int i = 0; i < 4; i++) af[i]  = *(const bf8*)(A + i * 16 * 256 + k0);
#pragma unroll
        for (int j = 0; j < 4; j++) bvf[j] = *(const bf8*)(B + j * 16 * 256 + k0);
#pragma unroll
        for (int i = 0; i < 4; i++)
#pragma unroll
            for (int j = 0; j < 4; j++)
                acc[i][j] = __builtin_amdgcn_mfma_f32_16x16x32_bf16(af[i], bvf[j], acc[i][j], 0, 0, 0);
    }
    int lbase = lt * 256 + w * 64;
#pragma unroll
    for (int i = 0; i < 4; i++) {
#pragma unroll
        for (int r = 0; r < 4; r++) {
            int j = jt * 64 + i * 16 + quad * 4 + r;
            float bias = pb[j];
            float* orow = out + ((size_t)b * 256 + j) * 4096;
#pragma unroll
            for (int jf = 0; jf < 4; jf++) {
                int ll = lbase + jf * 16 + ln15;
                orow[ll] = acc[i][jf][r] + bias;
            }
        }
    }
}

extern "C" void kernel_launch(void* const* d_in, const int* in_sizes, int n_in,
                              void* d_out, int out_size, void* d_ws, size_t ws_size,
                              hipStream_t stream) {
    const float* x    = (const float*)d_in[0];
    const float* ln_g = (const float*)d_in[1];
    const float* ln_b = (const float*)d_in[2];
    const float* wqkv = (const float*)d_in[3];
    const float* pw   = (const float*)d_in[4];
    const float* pb   = (const float*)d_in[5];
    const float* lw1  = (const float*)d_in[6];
    const float* lb1  = (const float*)d_in[7];
    const float* lw2  = (const float*)d_in[8];
    const float* lb2  = (const float*)d_in[9];

    float* ws = (float*)d_ws;
    // Workspace layout:
    //   [ws+65536 ..): xnb bf16 (8,388,608 shorts; reused as xcat bf16 after k_qkv)
    //                  + wb bf16 (196,608 shorts) + pwb bf16 (65,536 shorts)
    //   qw/kw/vw: unchanged region after the xn block
    unsigned short* xnb = (unsigned short*)(ws + 65536);
    unsigned short* wb  = xnb + 8388608;
    unsigned short* pwb = wb + 196608;
    unsigned short* qw  = (unsigned short*)(ws + 65536 + 8388608);
    unsigned short* kw  = qw + 8388608;
    unsigned short* vw  = kw + 8388608;
    unsigned short* xcat = xnb;   // overwrites xnb after k_qkv (stream-ordered)
    float* out  = (float*)d_out;
    float* attn = out + 8388608;

    k_wcvt<<<96, 256, 0, stream>>>(wqkv, wb);
    k_pcvt<<<256, 256, 0, stream>>>(pw, pwb);
    k_ln_t<<<dim3(128, 8), 256, 0, stream>>>(x, ln_g, ln_b, xnb);
    k_qkv<<<dim3(12, 16, 8), 256, 0, stream>>>(wb, xnb, qw, kw, vw);
    k_attn<<<1024, 256, 0, stream>>>(qw, kw, vw, lw1, lb1, lw2, lb2, attn, xcat);
    k_proj<<<dim3(4, 16, 8), 256, 0, stream>>>(pwb, pb, xcat, out);
}

// Round 4
// 505.178 us; speedup vs baseline: 1.3451x; 1.0266x over previous
//
#include <hip/hip_runtime.h>
#include <math.h>

typedef short bf8 __attribute__((ext_vector_type(8)));
typedef float f4  __attribute__((ext_vector_type(4)));

__device__ inline float b2f(unsigned short u) {
    return __uint_as_float(((unsigned int)u) << 16);
}
__device__ inline unsigned short f2b(float f) {
    unsigned int u = __float_as_uint(f);
    u = (u + 0x7fffu + ((u >> 16) & 1u)) >> 16;
    return (unsigned short)u;
}

// ---------------- K1: fused LayerNorm + transpose to bf16 [B, L, C] ----------------
__global__ __launch_bounds__(256) void k_ln_t(const float* __restrict__ x,
                                              const float* __restrict__ g,
                                              const float* __restrict__ beta,
                                              unsigned short* __restrict__ xnb) {
    __shared__ float xt[32 * 261];   // pitch 261 (odd dword stride) + per-element XOR swizzle
    __shared__ float ps[8][32];
    __shared__ float ps2[8][32];
    __shared__ float ms[32];
    __shared__ float rs[32];
    int l0 = blockIdx.x * 32, b = blockIdx.y;
    int tid = threadIdx.x;
    int tl = tid & 31, c0 = tid >> 5;      // c0 in 0..7
    const float* xb = x + (size_t)b * 1048576 + l0 + tl;
    float s = 0.f, s2 = 0.f;
#pragma unroll 8
    for (int rr = 0; rr < 32; ++rr) {
        int c = rr * 8 + c0;
        float v = xb[(size_t)c * 4096];            // wave: 32 consecutive l, coalesced
        int cm = c ^ (((rr >> 2) & 7) << 2);       // swizzle bits2-4 by c-bits5-7
        xt[tl * 261 + cm] = v;
        s += v; s2 += v * v;
    }
    ps[c0][tl] = s; ps2[c0][tl] = s2;
    __syncthreads();
    if (tid < 32) {
        float t = 0.f, t2 = 0.f;
#pragma unroll
        for (int j = 0; j < 8; ++j) { t += ps[j][tid]; t2 += ps2[j][tid]; }
        float m = t * (1.f / 256.f);
        float var = t2 * (1.f / 256.f) - m * m;
        ms[tid] = m;
        rs[tid] = rsqrtf(var + 1e-4f);
    }
    __syncthreads();
    // write phase: thread owns (l = tid>>3, c-chunk = (tid&7)*32) -> 64B contiguous
    int lw = tid >> 3, cc = (tid & 7) * 32;
    int xr = (tid & 7) << 2;                        // = ((c>>5)&7)<<2 for this chunk
    float m = ms[lw], r = rs[lw];
    unsigned short* dst = xnb + ((size_t)b * 4096 + l0 + lw) * 256 + cc;
#pragma unroll
    for (int q4 = 0; q4 < 4; ++q4) {
        int cb = cc + q4 * 8;
        float gv[8], bv[8];
        *(float4*)(gv)     = *(const float4*)(g + cb);
        *(float4*)(gv + 4) = *(const float4*)(g + cb + 4);
        *(float4*)(bv)     = *(const float4*)(beta + cb);
        *(float4*)(bv + 4) = *(const float4*)(beta + cb + 4);
        union { unsigned short u[8]; uint4 v; } pk;
#pragma unroll
        for (int e = 0; e < 8; ++e) {
            int cm = (cb + e) ^ xr;
            pk.u[e] = f2b((xt[lw * 261 + cm] - m) * r * gv[e] + bv[e]);
        }
        *(uint4*)(dst + q4 * 8) = pk.v;
    }
}

// ---------------- K2a: wqkv fp32 -> bf16 ----------------
__global__ __launch_bounds__(256) void k_wcvt(const float* __restrict__ w,
                                              unsigned short* __restrict__ wb) {
    int i = (blockIdx.x * 256 + threadIdx.x) * 8;
    float4 a = *(const float4*)(w + i);
    float4 c = *(const float4*)(w + i + 4);
    union { unsigned short u[8]; uint4 v; } r;
    r.u[0] = f2b(a.x); r.u[1] = f2b(a.y); r.u[2] = f2b(a.z); r.u[3] = f2b(a.w);
    r.u[4] = f2b(c.x); r.u[5] = f2b(c.y); r.u[6] = f2b(c.z); r.u[7] = f2b(c.w);
    *(uint4*)(wb + i) = r.v;
}

// ---------------- K2b: proj_w fp32 -> bf16 with head-grouped column permutation ----
// pwb[o][c'] = pw[o][c], c' = br*128 + head*32 + d  <->  c = br*128 + d*4 + head
__global__ __launch_bounds__(256) void k_pcvt(const float* __restrict__ pw,
                                              unsigned short* __restrict__ pwb) {
    int idx = blockIdx.x * 256 + threadIdx.x;   // 65536 total
    int o = idx >> 8, cp = idx & 255;
    int br = cp >> 7, head = (cp >> 5) & 3, d = cp & 31;
    int c = br * 128 + d * 4 + head;
    pwb[idx] = f2b(pw[o * 256 + c]);
}

// ---------------- K3: qkv GEMM (bf16 MFMA) + LDS-staged coalesced window scatter --
// Grid (lt, b, jt): jt-blocks sharing a B-tile differ by 128 in linear bid (=0 mod 8)
// -> same XCD -> B-tile fetched once per XCD; d0/d16 partner blocks merge lines in L2.
// Epilogue: acc -> LDS tile [64 j][256 l] (pitch 266 shorts, <=2-way banks) -> 32B
// coalesced uint4-pair stores in the q/k [pos][d] / v [d][pos] window layouts.
__global__ __launch_bounds__(256) void k_qkv(const unsigned short* __restrict__ wb,
                                             const unsigned short* __restrict__ xnb,
                                             unsigned short* __restrict__ qw,
                                             unsigned short* __restrict__ kw,
                                             unsigned short* __restrict__ vw) {
    __shared__ unsigned short sj[64 * 266];   // 34048 B
    int lt = blockIdx.x, b = blockIdx.y, jt = blockIdx.z;
    int tid = threadIdx.x;
    int w = tid >> 6, lane = tid & 63;
    int ln15 = lane & 15, quad = lane >> 4;
    const unsigned short* A = wb + (size_t)jt * 64 * 256 + ln15 * 256 + quad * 8;
    const unsigned short* B = xnb + ((size_t)b * 4096 + lt * 256 + w * 64 + ln15) * 256 + quad * 8;
    const f4 z = {0.f, 0.f, 0.f, 0.f};
    f4 acc[4][4];
#pragma unroll
    for (int i = 0; i < 4; i++)
#pragma unroll
        for (int j = 0; j < 4; j++) acc[i][j] = z;
#pragma unroll 2
    for (int k0 = 0; k0 < 256; k0 += 32) {
        bf8 af[4], bvf[4];
#pragma unroll
        for (int i = 0; i < 4; i++) af[i]  = *(const bf8*)(A + i * 16 * 256 + k0);
#pragma unroll
        for (int j = 0; j < 4; j++) bvf[j] = *(const bf8*)(B + j * 16 * 256 + k0);
#pragma unroll
        for (int i = 0; i < 4; i++)
#pragma unroll
            for (int j = 0; j < 4; j++)
                acc[i][j] = __builtin_amdgcn_mfma_f32_16x16x32_bf16(af[i], bvf[j], acc[i][j], 0, 0, 0);
    }
    // block-uniform decomposition: j = jt*64 + jlocal
    // sel 0=q 1=k 2=v; d = d0 + (jlocal>>2); head = jlocal&3
    int sel = jt >> 2;
    int branch = (jt >> 1) & 1;
    int d0 = (jt & 1) * 16;
    float sc = (sel == 0) ? 0.125f : 1.f;
    // stage acc tile to LDS: sj[jlocal][llocal]
#pragma unroll
    for (int i = 0; i < 4; i++)
#pragma unroll
        for (int jf = 0; jf < 4; jf++) {
            int ll = w * 64 + jf * 16 + ln15;
#pragma unroll
            for (int r = 0; r < 4; r++)
                sj[(i * 16 + quad * 4 + r) * 266 + ll] = f2b(acc[i][jf][r] * sc);
        }
    __syncthreads();

    if (sel < 2) {
        unsigned short* dst = (sel == 0) ? qw : kw;
        if (branch == 0) {
            // 16 windows x 16 consecutive pos (pos = lt*16 + posl); llocal(win,posl)
            int head = tid & 3, win = (tid >> 2) & 15, pgrp = tid >> 6;
            size_t basewh = (((size_t)b * 16 + win) * 4 + head) * 8192;
#pragma unroll
            for (int pp = 0; pp < 4; ++pp) {
                int posl = pgrp * 4 + pp;
                int llb = (posl >> 2) * 64 + win * 4 + (posl & 3);
                union { unsigned short u[16]; uint4 v[2]; } pk;
#pragma unroll
                for (int dl = 0; dl < 16; ++dl) {
                    int jl = (dl >> 2) * 16 + (dl & 3) * 4 + head;
                    pk.u[dl] = sj[jl * 266 + llb];
                }
                unsigned short* o = dst + basewh + (size_t)(lt * 16 + posl) * 32 + d0;
                *(uint4*)(o)     = pk.v[0];
                *(uint4*)(o + 8) = pk.v[1];
            }
        } else {
            // one window (win = lt), pos = llocal 0..255
            int head = tid & 3, p16 = tid >> 2;   // 0..63
            size_t basewh = (((size_t)128 + b * 16 + lt) * 4 + head) * 8192;
#pragma unroll
            for (int it = 0; it < 4; ++it) {
                int pos = p16 + it * 64;
                union { unsigned short u[16]; uint4 v[2]; } pk;
#pragma unroll
                for (int dl = 0; dl < 16; ++dl) {
                    int jl = (dl >> 2) * 16 + (dl & 3) * 4 + head;
                    pk.u[dl] = sj[jl * 266 + pos];
                }
                unsigned short* o = dst + basewh + (size_t)pos * 32 + d0;
                *(uint4*)(o)     = pk.v[0];
                *(uint4*)(o + 8) = pk.v[1];
            }
        }
    } else {
        if (branch == 0) {
            int head = tid & 3, win = (tid >> 2) & 15, dgrp = tid >> 6;
#pragma unroll
            for (int dd = 0; dd < 4; ++dd) {
                int dl = dgrp * 4 + dd;
                int jl = (dl >> 2) * 16 + (dl & 3) * 4 + head;
                union { unsigned short u[16]; uint4 v[2]; } pk;
#pragma unroll
                for (int posl = 0; posl < 16; ++posl) {
                    int llb = (posl >> 2) * 64 + win * 4 + (posl & 3);
                    pk.u[posl] = sj[jl * 266 + llb];
                }
                unsigned short* o = vw + ((((size_t)b * 16 + win) * 4 + head) * 32 + d0 + dl) * 256 + lt * 16;
                *(uint4*)(o)     = pk.v[0];
                *(uint4*)(o + 8) = pk.v[1];
            }
        } else {
            int head = tid & 3, dl = (tid >> 2) & 15, pc = tid >> 6;
            int jl = (dl >> 2) * 16 + (dl & 3) * 4 + head;
#pragma unroll
            for (int it = 0; it < 4; ++it) {
                int pos0 = pc * 64 + it * 16;
                union { unsigned short u[16]; uint4 v[2]; } pk;
#pragma unroll
                for (int pp = 0; pp < 16; ++pp)
                    pk.u[pp] = sj[jl * 266 + pos0 + pp];
                unsigned short* o = vw + ((((size_t)128 + b * 16 + lt) * 4 + head) * 32 + d0 + dl) * 256 + pos0;
                *(uint4*)(o)     = pk.v[0];
                *(uint4*)(o + 8) = pk.v[1];
            }
        }
    }
}

// ---------------- K4: MFMA attention + LePE ----------------
// xcat bf16 [b][l][c'], c' = branch*128 + head*32 + d (head-grouped -> 64B
// contiguous per thread-position, written as 4x uint4).
__global__ __launch_bounds__(256, 3) void k_attn(const unsigned short* __restrict__ qw,
                                                 const unsigned short* __restrict__ kw,
                                                 const unsigned short* __restrict__ vw,
                                                 const float* __restrict__ lw1,
                                                 const float* __restrict__ lb1,
                                                 const float* __restrict__ lw2,
                                                 const float* __restrict__ lb2,
                                                 float* __restrict__ attn_out,
                                                 unsigned short* __restrict__ xcat) {
    __shared__ __align__(16) char smem[49792];
    float*          olds = (float*)smem;            // 32*257 floats (O transpose; first 4KB = P staging)
    unsigned short* vt   = (unsigned short*)(smem + 32896);  // 32 rows * pitch 264 bf16

    int bid = blockIdx.x;
    int branch = bid >> 9;
    int bw = (bid >> 2) & 127;
    int head = bid & 3;
    int tid = threadIdx.x;
    int w = tid >> 6, lane = tid & 63;
    int ln15 = lane & 15, quad = lane >> 4;
    int rowbase = w * 64;

    size_t base = (((size_t)branch * 128 + bw) * 4 + head) * 8192;
    const unsigned short* qb = qw + base;   // [pos][d]
    const unsigned short* kb = kw + base;   // [pos][d]
    const unsigned short* vb = vw + base;   // [d][pos]

    // stage V into LDS (pitch 264)
    {
        int d = tid >> 3, ck = (tid & 7) * 32;
        const uint4* s = (const uint4*)(vb + d * 256 + ck);
        uint4* dst = (uint4*)(vt + d * 264 + ck);
        dst[0] = s[0]; dst[1] = s[1]; dst[2] = s[2]; dst[3] = s[3];
    }

    // Q fragments (A-layout): lane holds Q[row=ln15][k=quad*8..+8]
    bf8 qf[4];
#pragma unroll
    for (int rt = 0; rt < 4; rt++)
        qf[rt] = *(const bf8*)(qb + (rowbase + rt * 16 + ln15) * 32 + quad * 8);

    const f4 z = {0.f, 0.f, 0.f, 0.f};

    // ---- pass 1: row sums of exp(s) ----
    f4 lsum[4] = {z, z, z, z};
    for (int jtile = 0; jtile < 16; jtile++) {
        bf8 kf = *(const bf8*)(kb + (jtile * 16 + ln15) * 32 + quad * 8);
#pragma unroll
        for (int rt = 0; rt < 4; rt++) {
            f4 s = __builtin_amdgcn_mfma_f32_16x16x32_bf16(qf[rt], kf, z, 0, 0, 0);
            lsum[rt].x += __expf(s.x);
            lsum[rt].y += __expf(s.y);
            lsum[rt].z += __expf(s.z);
            lsum[rt].w += __expf(s.w);
        }
    }
    f4 inv[4];
#pragma unroll
    for (int rt = 0; rt < 4; rt++) {
        float a0 = lsum[rt].x, a1 = lsum[rt].y, a2 = lsum[rt].z, a3 = lsum[rt].w;
#pragma unroll
        for (int m = 1; m < 16; m <<= 1) {
            a0 += __shfl_xor(a0, m); a1 += __shfl_xor(a1, m);
            a2 += __shfl_xor(a2, m); a3 += __shfl_xor(a3, m);
        }
        inv[rt].x = 1.f / a0; inv[rt].y = 1.f / a1;
        inv[rt].z = 1.f / a2; inv[rt].w = 1.f / a3;
    }

    __syncthreads();   // V staged before any vt read

    // ---- pass 2: recompute S, write attn, PV via MFMA ----
    unsigned short* plw = ((unsigned short*)olds) + w * 512;  // 16x32 bf16 P staging per wave
    float* abase = attn_out + (size_t)branch * 33554432ull
                 + ((size_t)(bw * 4 + head)) * 65536;
    f4 oacc[4][2] = {{z, z}, {z, z}, {z, z}, {z, z}};
    for (int t = 0; t < 8; t++) {
        int c0 = t * 32;
        bf8 kf0 = *(const bf8*)(kb + (c0 + ln15) * 32 + quad * 8);
        bf8 kf1 = *(const bf8*)(kb + (c0 + 16 + ln15) * 32 + quad * 8);
        bf8 vf0 = *(const bf8*)(vt + ln15 * 264 + c0 + quad * 8);
        bf8 vf1 = *(const bf8*)(vt + (16 + ln15) * 264 + c0 + quad * 8);
#pragma unroll
        for (int rt = 0; rt < 4; rt++) {
            f4 s0 = __builtin_amdgcn_mfma_f32_16x16x32_bf16(qf[rt], kf0, z, 0, 0, 0);
            f4 s1 = __builtin_amdgcn_mfma_f32_16x16x32_bf16(qf[rt], kf1, z, 0, 0, 0);
            f4 p0, p1;
            p0.x = __expf(s0.x) * inv[rt].x; p0.y = __expf(s0.y) * inv[rt].y;
            p0.z = __expf(s0.z) * inv[rt].z; p0.w = __expf(s0.w) * inv[rt].w;
            p1.x = __expf(s1.x) * inv[rt].x; p1.y = __expf(s1.y) * inv[rt].y;
            p1.z = __expf(s1.z) * inv[rt].z; p1.w = __expf(s1.w) * inv[rt].w;
            float* ar = abase + (size_t)(rowbase + rt * 16 + quad * 4) * 256 + c0 + ln15;
            ar[0]   = p0.x; ar[256] = p0.y; ar[512] = p0.z; ar[768] = p0.w;
            ar[16]  = p1.x; ar[272] = p1.y; ar[528] = p1.z; ar[784] = p1.w;
            // stage P (bf16, A-layout source tile 16 rows x 32 cols, pitch 32)
            plw[(quad * 4 + 0) * 32 + ln15]      = f2b(p0.x);
            plw[(quad * 4 + 1) * 32 + ln15]      = f2b(p0.y);
            plw[(quad * 4 + 2) * 32 + ln15]      = f2b(p0.z);
            plw[(quad * 4 + 3) * 32 + ln15]      = f2b(p0.w);
            plw[(quad * 4 + 0) * 32 + 16 + ln15] = f2b(p1.x);
            plw[(quad * 4 + 1) * 32 + 16 + ln15] = f2b(p1.y);
            plw[(quad * 4 + 2) * 32 + 16 + ln15] = f2b(p1.z);
            plw[(quad * 4 + 3) * 32 + 16 + ln15] = f2b(p1.w);
            bf8 pf = *(const bf8*)(plw + ln15 * 32 + quad * 8);
            oacc[rt][0] = __builtin_amdgcn_mfma_f32_16x16x32_bf16(pf, vf0, oacc[rt][0], 0, 0, 0);
            oacc[rt][1] = __builtin_amdgcn_mfma_f32_16x16x32_bf16(pf, vf1, oacc[rt][1], 0, 0, 0);
        }
    }

    __syncthreads();   // all P staging reads done before O overwrites olds
    // O (C-layout) -> olds[d * 257 + pos]
#pragma unroll
    for (int rt = 0; rt < 4; rt++)
#pragma unroll
        for (int dt = 0; dt < 2; dt++) {
            int d = dt * 16 + ln15;
            int r = rowbase + rt * 16 + quad * 4;
            olds[d * 257 + r + 0] = oacc[rt][dt][0];
            olds[d * 257 + r + 1] = oacc[rt][dt][1];
            olds[d * 257 + r + 2] = oacc[rt][dt][2];
            olds[d * 257 + r + 3] = oacc[rt][dt][3];
        }
    __syncthreads();

    // ---- LePE + xcat write: thread = position; bf16 [b][l][c'] head-grouped ----
    const float* lw = branch ? lw2 : lw1;
    const float* lb = branch ? lb2 : lb1;
    int p = tid;
    int hs, ws_;
    if (branch == 0) { hs = p >> 2; ws_ = p & 3; }
    else             { hs = p >> 6; ws_ = p & 63; }
    int win = bw & 15, b = bw >> 4;
    int row, col;
    if (branch == 0) { row = p >> 2; col = (win << 2) | (p & 3); }
    else             { row = (win << 2) | (p >> 6); col = p & 63; }
    size_t lpix = (size_t)row * 64 + col;
    unsigned short* xd = xcat + (((size_t)b * 4096 + lpix) * 256) + branch * 128 + head * 32;
#pragma unroll
    for (int dg = 0; dg < 4; ++dg) {
        union { unsigned short u[8]; uint4 v; } pk;
#pragma unroll
        for (int dd = 0; dd < 8; ++dd) {
            int d = dg * 8 + dd;
            float acc = lb[d * 4 + head];
#pragma unroll
            for (int ky = 0; ky < 3; ky++) {
#pragma unroll
                for (int kx = 0; kx < 3; kx++) {
                    int ny = hs + ky - 1, nx = ws_ + kx - 1;
                    bool ok; int np;
                    if (branch == 0) { ok = (ny >= 0 && ny < 64 && nx >= 0 && nx < 4);  np = (ny << 2) | (nx & 3); }
                    else             { ok = (ny >= 0 && ny < 4  && nx >= 0 && nx < 64); np = (ny << 6) | (nx & 63); }
                    if (ok) acc += lw[(d * 4 + head) * 9 + ky * 3 + kx] * b2f(vt[d * 264 + np]);
                }
            }
            pk.u[dd] = f2b(olds[d * 257 + p] + acc);
        }
        *(uint4*)(xd + dg * 8) = pk.v;
    }
}

// ---------------- K5: projection GEMM (bf16 MFMA) ----------------
// out[b][j][l] = sum_c' pwb[j][c'] * xcat[b][l][c'] + pb[j]
__global__ __launch_bounds__(256) void k_proj(const unsigned short* __restrict__ pwb,
                                              const float* __restrict__ pb,
                                              const unsigned short* __restrict__ xcat,
                                              float* __restrict__ out) {
    int jt = blockIdx.x, lt = blockIdx.y, b = blockIdx.z;
    int tid = threadIdx.x;
    int w = tid >> 6, lane = tid & 63;
    int ln15 = lane & 15, quad = lane >> 4;
    const unsigned short* A = pwb + (size_t)jt * 64 * 256 + ln15 * 256 + quad * 8;
    const unsigned short* B = xcat + ((size_t)b * 4096 + lt * 256 + w * 64 + ln15) * 256 + quad * 8;
    const f4 z = {0.f, 0.f, 0.f, 0.f};
    f4 acc[4][4];
#pragma unroll
    for (int i = 0; i < 4; i++)
#pragma unroll
        for (int j = 0; j < 4; j++) acc[i][j] = z;
#pragma unroll 2
    for (int k0 = 0; k0 < 256; k0 += 32) {
        bf8 af[4], bvf[4];
#pragma unroll
        for (int i = 0; i < 4; i++) af[i]  = *(const bf8*)(A + i * 16 * 256 + k0);
#pragma unroll
        for (int j = 0; j < 4; j++) bvf[j] = *(const bf8*)(B + j * 16 * 256 + k0);
#pragma unroll
        for (int i = 0; i < 4; i++)
#pragma unroll
            for (int j = 0; j < 4; j++)
                acc[i][j] = __builtin_amdgcn_mfma_f32_16x16x32_bf16(af[i], bvf[j], acc[i][j], 0, 0, 0);
    }
    int lbase = lt * 256 + w * 64;
#pragma unroll
    for (int i = 0; i < 4; i++) {
#pragma unroll
        for (int r = 0; r < 4; r++) {
            int j = jt * 64 + i * 16 + quad * 4 + r;
            float bias = pb[j];
            float* orow = out + ((size_t)b * 256 + j) * 4096;
#pragma unroll
            for (int jf = 0; jf < 4; jf++) {
                int ll = lbase + jf * 16 + ln15;
                orow[ll] = acc[i][jf][r] + bias;
            }
        }
    }
}

extern "C" void kernel_launch(void* const* d_in, const int* in_sizes, int n_in,
                              void* d_out, int out_size, void* d_ws, size_t ws_size,
                              hipStream_t stream) {
    const float* x    = (const float*)d_in[0];
    const float* ln_g = (const float*)d_in[1];
    const float* ln_b = (const float*)d_in[2];
    const float* wqkv = (const float*)d_in[3];
    const float* pw   = (const float*)d_in[4];
    const float* pb   = (const float*)d_in[5];
    const float* lw1  = (const float*)d_in[6];
    const float* lb1  = (const float*)d_in[7];
    const float* lw2  = (const float*)d_in[8];
    const float* lb2  = (const float*)d_in[9];

    float* ws = (float*)d_ws;
    // Workspace layout:
    //   [ws+65536 ..): xnb bf16 (8,388,608 shorts; reused as xcat bf16 after k_qkv)
    //                  + wb bf16 (196,608 shorts) + pwb bf16 (65,536 shorts)
    //   qw/kw/vw: unchanged region after the xn block
    unsigned short* xnb = (unsigned short*)(ws + 65536);
    unsigned short* wb  = xnb + 8388608;
    unsigned short* pwb = wb + 196608;
    unsigned short* qw  = (unsigned short*)(ws + 65536 + 8388608);
    unsigned short* kw  = qw + 8388608;
    unsigned short* vw  = kw + 8388608;
    unsigned short* xcat = xnb;   // overwrites xnb after k_qkv (stream-ordered)
    float* out  = (float*)d_out;
    float* attn = out + 8388608;

    k_wcvt<<<96, 256, 0, stream>>>(wqkv, wb);
    k_pcvt<<<256, 256, 0, stream>>>(pw, pwb);
    k_ln_t<<<dim3(128, 8), 256, 0, stream>>>(x, ln_g, ln_b, xnb);
    k_qkv<<<dim3(16, 8, 12), 256, 0, stream>>>(wb, xnb, qw, kw, vw);
    k_attn<<<1024, 256, 0, stream>>>(qw, kw, vw, lw1, lb1, lw2, lb2, attn, xcat);
    k_proj<<<dim3(4, 16, 8), 256, 0, stream>>>(pwb, pb, xcat, out);
}

// Round 5
// 479.728 us; speedup vs baseline: 1.4165x; 1.0531x over previous
//
#include <hip/hip_runtime.h>
#include <math.h>

typedef short bf8 __attribute__((ext_vector_type(8)));
typedef float f4  __attribute__((ext_vector_type(4)));

__device__ inline float b2f(unsigned short u) {
    return __uint_as_float(((unsigned int)u) << 16);
}
__device__ inline unsigned short f2b(float f) {
    unsigned int u = __float_as_uint(f);
    u = (u + 0x7fffu + ((u >> 16) & 1u)) >> 16;
    return (unsigned short)u;
}

// ---------------- K1: fused LayerNorm + transpose to bf16 [B, L, C] ----------------
__global__ __launch_bounds__(256) void k_ln_t(const float* __restrict__ x,
                                              const float* __restrict__ g,
                                              const float* __restrict__ beta,
                                              unsigned short* __restrict__ xnb) {
    __shared__ float xt[32 * 261];   // pitch 261 (odd dword stride) + per-element XOR swizzle
    __shared__ float ps[8][32];
    __shared__ float ps2[8][32];
    __shared__ float ms[32];
    __shared__ float rs[32];
    int l0 = blockIdx.x * 32, b = blockIdx.y;
    int tid = threadIdx.x;
    int tl = tid & 31, c0 = tid >> 5;      // c0 in 0..7
    const float* xb = x + (size_t)b * 1048576 + l0 + tl;
    float s = 0.f, s2 = 0.f;
#pragma unroll 8
    for (int rr = 0; rr < 32; ++rr) {
        int c = rr * 8 + c0;
        float v = xb[(size_t)c * 4096];            // wave: 32 consecutive l, coalesced
        int cm = c ^ (((rr >> 2) & 7) << 2);       // swizzle bits2-4 by c-bits5-7
        xt[tl * 261 + cm] = v;
        s += v; s2 += v * v;
    }
    ps[c0][tl] = s; ps2[c0][tl] = s2;
    __syncthreads();
    if (tid < 32) {
        float t = 0.f, t2 = 0.f;
#pragma unroll
        for (int j = 0; j < 8; ++j) { t += ps[j][tid]; t2 += ps2[j][tid]; }
        float m = t * (1.f / 256.f);
        float var = t2 * (1.f / 256.f) - m * m;
        ms[tid] = m;
        rs[tid] = rsqrtf(var + 1e-4f);
    }
    __syncthreads();
    // write phase: thread owns (l = tid>>3, c-chunk = (tid&7)*32) -> 64B contiguous
    int lw = tid >> 3, cc = (tid & 7) * 32;
    int xr = (tid & 7) << 2;                        // = ((c>>5)&7)<<2 for this chunk
    float m = ms[lw], r = rs[lw];
    unsigned short* dst = xnb + ((size_t)b * 4096 + l0 + lw) * 256 + cc;
#pragma unroll
    for (int q4 = 0; q4 < 4; ++q4) {
        int cb = cc + q4 * 8;
        float gv[8], bv[8];
        *(float4*)(gv)     = *(const float4*)(g + cb);
        *(float4*)(gv + 4) = *(const float4*)(g + cb + 4);
        *(float4*)(bv)     = *(const float4*)(beta + cb);
        *(float4*)(bv + 4) = *(const float4*)(beta + cb + 4);
        union { unsigned short u[8]; uint4 v; } pk;
#pragma unroll
        for (int e = 0; e < 8; ++e) {
            int cm = (cb + e) ^ xr;
            pk.u[e] = f2b((xt[lw * 261 + cm] - m) * r * gv[e] + bv[e]);
        }
        *(uint4*)(dst + q4 * 8) = pk.v;
    }
}

// ---------------- K2a: wqkv fp32 -> bf16 ----------------
__global__ __launch_bounds__(256) void k_wcvt(const float* __restrict__ w,
                                              unsigned short* __restrict__ wb) {
    int i = (blockIdx.x * 256 + threadIdx.x) * 8;
    float4 a = *(const float4*)(w + i);
    float4 c = *(const float4*)(w + i + 4);
    union { unsigned short u[8]; uint4 v; } r;
    r.u[0] = f2b(a.x); r.u[1] = f2b(a.y); r.u[2] = f2b(a.z); r.u[3] = f2b(a.w);
    r.u[4] = f2b(c.x); r.u[5] = f2b(c.y); r.u[6] = f2b(c.z); r.u[7] = f2b(c.w);
    *(uint4*)(wb + i) = r.v;
}

// ---------------- K2b: proj_w fp32 -> bf16 with head-grouped column permutation ----
// pwb[o][c'] = pw[o][c], c' = br*128 + head*32 + d  <->  c = br*128 + d*4 + head
__global__ __launch_bounds__(256) void k_pcvt(const float* __restrict__ pw,
                                              unsigned short* __restrict__ pwb) {
    int idx = blockIdx.x * 256 + threadIdx.x;   // 65536 total
    int o = idx >> 8, cp = idx & 255;
    int br = cp >> 7, head = (cp >> 5) & 3, d = cp & 31;
    int c = br * 128 + d * 4 + head;
    pwb[idx] = f2b(pw[o * 256 + c]);
}

// ---------------- K3: qkv GEMM (bf16 MFMA) + LDS-staged coalesced window scatter --
__global__ __launch_bounds__(256) void k_qkv(const unsigned short* __restrict__ wb,
                                             const unsigned short* __restrict__ xnb,
                                             unsigned short* __restrict__ qw,
                                             unsigned short* __restrict__ kw,
                                             unsigned short* __restrict__ vw) {
    __shared__ unsigned short sj[64 * 266];   // 34048 B
    int lt = blockIdx.x, b = blockIdx.y, jt = blockIdx.z;
    int tid = threadIdx.x;
    int w = tid >> 6, lane = tid & 63;
    int ln15 = lane & 15, quad = lane >> 4;
    const unsigned short* A = wb + (size_t)jt * 64 * 256 + ln15 * 256 + quad * 8;
    const unsigned short* B = xnb + ((size_t)b * 4096 + lt * 256 + w * 64 + ln15) * 256 + quad * 8;
    const f4 z = {0.f, 0.f, 0.f, 0.f};
    f4 acc[4][4];
#pragma unroll
    for (int i = 0; i < 4; i++)
#pragma unroll
        for (int j = 0; j < 4; j++) acc[i][j] = z;
#pragma unroll 2
    for (int k0 = 0; k0 < 256; k0 += 32) {
        bf8 af[4], bvf[4];
#pragma unroll
        for (int i = 0; i < 4; i++) af[i]  = *(const bf8*)(A + i * 16 * 256 + k0);
#pragma unroll
        for (int j = 0; j < 4; j++) bvf[j] = *(const bf8*)(B + j * 16 * 256 + k0);
#pragma unroll
        for (int i = 0; i < 4; i++)
#pragma unroll
            for (int j = 0; j < 4; j++)
                acc[i][j] = __builtin_amdgcn_mfma_f32_16x16x32_bf16(af[i], bvf[j], acc[i][j], 0, 0, 0);
    }
    // block-uniform decomposition: j = jt*64 + jlocal
    int sel = jt >> 2;
    int branch = (jt >> 1) & 1;
    int d0 = (jt & 1) * 16;
    float sc = (sel == 0) ? 0.125f : 1.f;
    // stage acc tile to LDS: sj[jlocal][llocal]
#pragma unroll
    for (int i = 0; i < 4; i++)
#pragma unroll
        for (int jf = 0; jf < 4; jf++) {
            int ll = w * 64 + jf * 16 + ln15;
#pragma unroll
            for (int r = 0; r < 4; r++)
                sj[(i * 16 + quad * 4 + r) * 266 + ll] = f2b(acc[i][jf][r] * sc);
        }
    __syncthreads();

    if (sel < 2) {
        unsigned short* dst = (sel == 0) ? qw : kw;
        if (branch == 0) {
            int head = tid & 3, win = (tid >> 2) & 15, pgrp = tid >> 6;
            size_t basewh = (((size_t)b * 16 + win) * 4 + head) * 8192;
#pragma unroll
            for (int pp = 0; pp < 4; ++pp) {
                int posl = pgrp * 4 + pp;
                int llb = (posl >> 2) * 64 + win * 4 + (posl & 3);
                union { unsigned short u[16]; uint4 v[2]; } pk;
#pragma unroll
                for (int dl = 0; dl < 16; ++dl) {
                    int jl = (dl >> 2) * 16 + (dl & 3) * 4 + head;
                    pk.u[dl] = sj[jl * 266 + llb];
                }
                unsigned short* o = dst + basewh + (size_t)(lt * 16 + posl) * 32 + d0;
                *(uint4*)(o)     = pk.v[0];
                *(uint4*)(o + 8) = pk.v[1];
            }
        } else {
            int head = tid & 3, p16 = tid >> 2;   // 0..63
            size_t basewh = (((size_t)128 + b * 16 + lt) * 4 + head) * 8192;
#pragma unroll
            for (int it = 0; it < 4; ++it) {
                int pos = p16 + it * 64;
                union { unsigned short u[16]; uint4 v[2]; } pk;
#pragma unroll
                for (int dl = 0; dl < 16; ++dl) {
                    int jl = (dl >> 2) * 16 + (dl & 3) * 4 + head;
                    pk.u[dl] = sj[jl * 266 + pos];
                }
                unsigned short* o = dst + basewh + (size_t)pos * 32 + d0;
                *(uint4*)(o)     = pk.v[0];
                *(uint4*)(o + 8) = pk.v[1];
            }
        }
    } else {
        if (branch == 0) {
            int head = tid & 3, win = (tid >> 2) & 15, dgrp = tid >> 6;
#pragma unroll
            for (int dd = 0; dd < 4; ++dd) {
                int dl = dgrp * 4 + dd;
                int jl = (dl >> 2) * 16 + (dl & 3) * 4 + head;
                union { unsigned short u[16]; uint4 v[2]; } pk;
#pragma unroll
                for (int posl = 0; posl < 16; ++posl) {
                    int llb = (posl >> 2) * 64 + win * 4 + (posl & 3);
                    pk.u[posl] = sj[jl * 266 + llb];
                }
                unsigned short* o = vw + ((((size_t)b * 16 + win) * 4 + head) * 32 + d0 + dl) * 256 + lt * 16;
                *(uint4*)(o)     = pk.v[0];
                *(uint4*)(o + 8) = pk.v[1];
            }
        } else {
            int head = tid & 3, dl = (tid >> 2) & 15, pc = tid >> 6;
            int jl = (dl >> 2) * 16 + (dl & 3) * 4 + head;
#pragma unroll
            for (int it = 0; it < 4; ++it) {
                int pos0 = pc * 64 + it * 16;
                union { unsigned short u[16]; uint4 v[2]; } pk;
#pragma unroll
                for (int pp = 0; pp < 16; ++pp)
                    pk.u[pp] = sj[jl * 266 + pos0 + pp];
                unsigned short* o = vw + ((((size_t)128 + b * 16 + lt) * 4 + head) * 32 + d0 + dl) * 256 + pos0;
                *(uint4*)(o)     = pk.v[0];
                *(uint4*)(o + 8) = pk.v[1];
            }
        }
    }
}

// ---------------- K4: MFMA attention + LePE ----------------
// LDS cut to 33,344 B (fp32 O-staging in two 16-d halves) -> 4 blocks/CU; grid
// 1024 = exactly 4/CU (no straggler round). Math bit-identical to prior version.
__global__ __launch_bounds__(256, 4) void k_attn(const unsigned short* __restrict__ qw,
                                                 const unsigned short* __restrict__ kw,
                                                 const unsigned short* __restrict__ vw,
                                                 const float* __restrict__ lw1,
                                                 const float* __restrict__ lb1,
                                                 const float* __restrict__ lw2,
                                                 const float* __restrict__ lb2,
                                                 float* __restrict__ attn_out,
                                                 unsigned short* __restrict__ xcat) {
    __shared__ __align__(16) char smem[33344];
    float*          olds = (float*)smem;            // 16*257 floats = 16448 B (first 4KB = P staging)
    unsigned short* vt   = (unsigned short*)(smem + 16448);  // 32 rows * pitch 264 bf16 = 16896 B

    int bid = blockIdx.x;
    int branch = bid >> 9;
    int bw = (bid >> 2) & 127;
    int head = bid & 3;
    int tid = threadIdx.x;
    int w = tid >> 6, lane = tid & 63;
    int ln15 = lane & 15, quad = lane >> 4;
    int rowbase = w * 64;

    size_t base = (((size_t)branch * 128 + bw) * 4 + head) * 8192;
    const unsigned short* qb = qw + base;   // [pos][d]
    const unsigned short* kb = kw + base;   // [pos][d]
    const unsigned short* vb = vw + base;   // [d][pos]

    // stage V into LDS (pitch 264)
    {
        int d = tid >> 3, ck = (tid & 7) * 32;
        const uint4* s = (const uint4*)(vb + d * 256 + ck);
        uint4* dst = (uint4*)(vt + d * 264 + ck);
        dst[0] = s[0]; dst[1] = s[1]; dst[2] = s[2]; dst[3] = s[3];
    }

    // Q fragments (A-layout): lane holds Q[row=ln15][k=quad*8..+8]
    bf8 qf[4];
#pragma unroll
    for (int rt = 0; rt < 4; rt++)
        qf[rt] = *(const bf8*)(qb + (rowbase + rt * 16 + ln15) * 32 + quad * 8);

    const f4 z = {0.f, 0.f, 0.f, 0.f};

    // ---- pass 1: row sums of exp(s) ----
    f4 lsum[4] = {z, z, z, z};
    for (int jtile = 0; jtile < 16; jtile++) {
        bf8 kf = *(const bf8*)(kb + (jtile * 16 + ln15) * 32 + quad * 8);
#pragma unroll
        for (int rt = 0; rt < 4; rt++) {
            f4 s = __builtin_amdgcn_mfma_f32_16x16x32_bf16(qf[rt], kf, z, 0, 0, 0);
            lsum[rt].x += __expf(s.x);
            lsum[rt].y += __expf(s.y);
            lsum[rt].z += __expf(s.z);
            lsum[rt].w += __expf(s.w);
        }
    }
    f4 inv[4];
#pragma unroll
    for (int rt = 0; rt < 4; rt++) {
        float a0 = lsum[rt].x, a1 = lsum[rt].y, a2 = lsum[rt].z, a3 = lsum[rt].w;
#pragma unroll
        for (int m = 1; m < 16; m <<= 1) {
            a0 += __shfl_xor(a0, m); a1 += __shfl_xor(a1, m);
            a2 += __shfl_xor(a2, m); a3 += __shfl_xor(a3, m);
        }
        inv[rt].x = 1.f / a0; inv[rt].y = 1.f / a1;
        inv[rt].z = 1.f / a2; inv[rt].w = 1.f / a3;
    }

    __syncthreads();   // V staged before any vt read

    // ---- pass 2: recompute S, write attn, PV via MFMA ----
    unsigned short* plw = ((unsigned short*)olds) + w * 512;  // 16x32 bf16 P staging per wave
    float* abase = attn_out + (size_t)branch * 33554432ull
                 + ((size_t)(bw * 4 + head)) * 65536;
    f4 oacc[4][2] = {{z, z}, {z, z}, {z, z}, {z, z}};
    for (int t = 0; t < 8; t++) {
        int c0 = t * 32;
        bf8 kf0 = *(const bf8*)(kb + (c0 + ln15) * 32 + quad * 8);
        bf8 kf1 = *(const bf8*)(kb + (c0 + 16 + ln15) * 32 + quad * 8);
        bf8 vf0 = *(const bf8*)(vt + ln15 * 264 + c0 + quad * 8);
        bf8 vf1 = *(const bf8*)(vt + (16 + ln15) * 264 + c0 + quad * 8);
#pragma unroll
        for (int rt = 0; rt < 4; rt++) {
            f4 s0 = __builtin_amdgcn_mfma_f32_16x16x32_bf16(qf[rt], kf0, z, 0, 0, 0);
            f4 s1 = __builtin_amdgcn_mfma_f32_16x16x32_bf16(qf[rt], kf1, z, 0, 0, 0);
            f4 p0, p1;
            p0.x = __expf(s0.x) * inv[rt].x; p0.y = __expf(s0.y) * inv[rt].y;
            p0.z = __expf(s0.z) * inv[rt].z; p0.w = __expf(s0.w) * inv[rt].w;
            p1.x = __expf(s1.x) * inv[rt].x; p1.y = __expf(s1.y) * inv[rt].y;
            p1.z = __expf(s1.z) * inv[rt].z; p1.w = __expf(s1.w) * inv[rt].w;
            float* ar = abase + (size_t)(rowbase + rt * 16 + quad * 4) * 256 + c0 + ln15;
            ar[0]   = p0.x; ar[256] = p0.y; ar[512] = p0.z; ar[768] = p0.w;
            ar[16]  = p1.x; ar[272] = p1.y; ar[528] = p1.z; ar[784] = p1.w;
            // stage P (bf16, A-layout source tile 16 rows x 32 cols, pitch 32)
            plw[(quad * 4 + 0) * 32 + ln15]      = f2b(p0.x);
            plw[(quad * 4 + 1) * 32 + ln15]      = f2b(p0.y);
            plw[(quad * 4 + 2) * 32 + ln15]      = f2b(p0.z);
            plw[(quad * 4 + 3) * 32 + ln15]      = f2b(p0.w);
            plw[(quad * 4 + 0) * 32 + 16 + ln15] = f2b(p1.x);
            plw[(quad * 4 + 1) * 32 + 16 + ln15] = f2b(p1.y);
            plw[(quad * 4 + 2) * 32 + 16 + ln15] = f2b(p1.z);
            plw[(quad * 4 + 3) * 32 + 16 + ln15] = f2b(p1.w);
            bf8 pf = *(const bf8*)(plw + ln15 * 32 + quad * 8);
            oacc[rt][0] = __builtin_amdgcn_mfma_f32_16x16x32_bf16(pf, vf0, oacc[rt][0], 0, 0, 0);
            oacc[rt][1] = __builtin_amdgcn_mfma_f32_16x16x32_bf16(pf, vf1, oacc[rt][1], 0, 0, 0);
        }
    }

    __syncthreads();   // all P staging reads done before O overwrites olds

    // ---- epilogue in two 16-d halves: O transpose (fp32) + LePE + xcat write ----
    const float* lw = branch ? lw2 : lw1;
    const float* lb = branch ? lb2 : lb1;
    int p = tid;
    int hs, ws_;
    if (branch == 0) { hs = p >> 2; ws_ = p & 3; }
    else             { hs = p >> 6; ws_ = p & 63; }
    int win = bw & 15, b = bw >> 4;
    int row, col;
    if (branch == 0) { row = p >> 2; col = (win << 2) | (p & 3); }
    else             { row = (win << 2) | (p >> 6); col = p & 63; }
    size_t lpix = (size_t)row * 64 + col;
    unsigned short* xd = xcat + (((size_t)b * 4096 + lpix) * 256) + branch * 128 + head * 32;

#pragma unroll
    for (int dt = 0; dt < 2; ++dt) {
        if (dt) __syncthreads();   // previous half's olds reads done
        // stage O half: olds[dlocal * 257 + pos], dlocal = ln15
#pragma unroll
        for (int rt = 0; rt < 4; rt++) {
            int r = rowbase + rt * 16 + quad * 4;
            olds[ln15 * 257 + r + 0] = oacc[rt][dt][0];
            olds[ln15 * 257 + r + 1] = oacc[rt][dt][1];
            olds[ln15 * 257 + r + 2] = oacc[rt][dt][2];
            olds[ln15 * 257 + r + 3] = oacc[rt][dt][3];
        }
        __syncthreads();
        // LePE + write 16 d of this half (two uint4 stores)
#pragma unroll
        for (int dg = 0; dg < 2; ++dg) {
            union { unsigned short u[8]; uint4 v; } pk;
#pragma unroll
            for (int dd = 0; dd < 8; ++dd) {
                int dl = dg * 8 + dd;
                int d = dt * 16 + dl;
                float acc = lb[d * 4 + head];
#pragma unroll
                for (int ky = 0; ky < 3; ky++) {
#pragma unroll
                    for (int kx = 0; kx < 3; kx++) {
                        int ny = hs + ky - 1, nx = ws_ + kx - 1;
                        bool ok; int np;
                        if (branch == 0) { ok = (ny >= 0 && ny < 64 && nx >= 0 && nx < 4);  np = (ny << 2) | (nx & 3); }
                        else             { ok = (ny >= 0 && ny < 4  && nx >= 0 && nx < 64); np = (ny << 6) | (nx & 63); }
                        if (ok) acc += lw[(d * 4 + head) * 9 + ky * 3 + kx] * b2f(vt[d * 264 + np]);
                    }
                }
                pk.u[dd] = f2b(olds[dl * 257 + p] + acc);
            }
            *(uint4*)(xd + dt * 16 + dg * 8) = pk.v;
        }
    }
}

// ---------------- K5: projection GEMM (bf16 MFMA) ----------------
__global__ __launch_bounds__(256) void k_proj(const unsigned short* __restrict__ pwb,
                                              const float* __restrict__ pb,
                                              const unsigned short* __restrict__ xcat,
                                              float* __restrict__ out) {
    int jt = blockIdx.x, lt = blockIdx.y, b = blockIdx.z;
    int tid = threadIdx.x;
    int w = tid >> 6, lane = tid & 63;
    int ln15 = lane & 15, quad = lane >> 4;
    const unsigned short* A = pwb + (size_t)jt * 64 * 256 + ln15 * 256 + quad * 8;
    const unsigned short* B = xcat + ((size_t)b * 4096 + lt * 256 + w * 64 + ln15) * 256 + quad * 8;
    const f4 z = {0.f, 0.f, 0.f, 0.f};
    f4 acc[4][4];
#pragma unroll
    for (int i = 0; i < 4; i++)
#pragma unroll
        for (int j = 0; j < 4; j++) acc[i][j] = z;
#pragma unroll 2
    for (int k0 = 0; k0 < 256; k0 += 32) {
        bf8 af[4], bvf[4];
#pragma unroll
        for (int i = 0; i < 4; i++) af[i]  = *(const bf8*)(A + i * 16 * 256 + k0);
#pragma unroll
        for (int j = 0; j < 4; j++) bvf[j] = *(const bf8*)(B + j * 16 * 256 + k0);
#pragma unroll
        for (int i = 0; i < 4; i++)
#pragma unroll
            for (int j = 0; j < 4; j++)
                acc[i][j] = __builtin_amdgcn_mfma_f32_16x16x32_bf16(af[i], bvf[j], acc[i][j], 0, 0, 0);
    }
    int lbase = lt * 256 + w * 64;
#pragma unroll
    for (int i = 0; i < 4; i++) {
#pragma unroll
        for (int r = 0; r < 4; r++) {
            int j = jt * 64 + i * 16 + quad * 4 + r;
            float bias = pb[j];
            float* orow = out + ((size_t)b * 256 + j) * 4096;
#pragma unroll
            for (int jf = 0; jf < 4; jf++) {
                int ll = lbase + jf * 16 + ln15;
                orow[ll] = acc[i][jf][r] + bias;
            }
        }
    }
}

extern "C" void kernel_launch(void* const* d_in, const int* in_sizes, int n_in,
                              void* d_out, int out_size, void* d_ws, size_t ws_size,
                              hipStream_t stream) {
    const float* x    = (const float*)d_in[0];
    const float* ln_g = (const float*)d_in[1];
    const float* ln_b = (const float*)d_in[2];
    const float* wqkv = (const float*)d_in[3];
    const float* pw   = (const float*)d_in[4];
    const float* pb   = (const float*)d_in[5];
    const float* lw1  = (const float*)d_in[6];
    const float* lb1  = (const float*)d_in[7];
    const float* lw2  = (const float*)d_in[8];
    const float* lb2  = (const float*)d_in[9];

    float* ws = (float*)d_ws;
    unsigned short* xnb = (unsigned short*)(ws + 65536);
    unsigned short* wb  = xnb + 8388608;
    unsigned short* pwb = wb + 196608;
    unsigned short* qw  = (unsigned short*)(ws + 65536 + 8388608);
    unsigned short* kw  = qw + 8388608;
    unsigned short* vw  = kw + 8388608;
    unsigned short* xcat = xnb;   // overwrites xnb after k_qkv (stream-ordered)
    float* out  = (float*)d_out;
    float* attn = out + 8388608;

    k_wcvt<<<96, 256, 0, stream>>>(wqkv, wb);
    k_pcvt<<<256, 256, 0, stream>>>(pw, pwb);
    k_ln_t<<<dim3(128, 8), 256, 0, stream>>>(x, ln_g, ln_b, xnb);
    k_qkv<<<dim3(16, 8, 12), 256, 0, stream>>>(wb, xnb, qw, kw, vw);
    k_attn<<<1024, 256, 0, stream>>>(qw, kw, vw, lw1, lb1, lw2, lb2, attn, xcat);
    k_proj<<<dim3(4, 16, 8), 256, 0, stream>>>(pwb, pb, xcat, out);
}